// Round 13
// baseline (254.054 us; speedup 1.0000x reference)
//
#include <hip/hip_runtime.h>
#include <hip/hip_bf16.h>

// KAN layer = GEMM: out[b,o] = sum_{i,k} T_k(tanh(x[b,i])) * W[o,i,k] + bias[o]
// v10 = v9 with A taken OUT of LDS: each lane loads its A-fragment (16B,
// 64B-aligned segments) global->register directly, distance-1 prefetch.
//   v9 counters: LDS 96 KB/step (~57% busy), MFMA 621 cyc (26.5%), and ~40%
//   intra-wave serialization at 1 wave/SIMD. Dropping A from LDS halves LDS
//   traffic (48 KB/step) and removes half the DMA ops; A re-reads come from
//   L2/L3 exactly as the old glds path did (FETCH unchanged).
//   Sync skeleton = v9's proven one: triple-buffered B, ONE s_barrier/iter,
//   counted vmcnt(12) (region = 4 B-stage + 8 A-loads = 12 VMEM ops exactly;
//   reorder-proof: the 12 newest are this region, so stage(T) always drains).
//   A-load consumption ordering is compiler-tracked register dataflow.
#define MD 4096
#define ND 1024
#define KD 8192
#define IN_F 1024

typedef __bf16 bf16x8 __attribute__((ext_vector_type(8)));
typedef float f32x4 __attribute__((ext_vector_type(4)));

// ---------------- Pass 1 (merged): basis + W convert ----------------
#define N_BASIS (MD * IN_F)
#define N_CONV ((ND * KD) / 8)

__global__ __launch_bounds__(256) void prep_kernel(
    const float* __restrict__ x, const float* __restrict__ w,
    __bf16* __restrict__ A, __bf16* __restrict__ B) {
  int i = blockIdx.x * blockDim.x + threadIdx.x;
  if (i < N_BASIS) {
    float t = tanhf(x[i]);
    float two_t = 2.0f * t;
    float T0 = 1.0f;
    float T1 = t;
    float T2 = two_t * T1 - T0;
    float T3 = two_t * T2 - T1;
    float T4 = two_t * T3 - T2;
    float T5 = two_t * T4 - T3;
    float T6 = two_t * T5 - T4;
    float T7 = two_t * T6 - T5;
    bf16x8 v;
    v[0] = (__bf16)T0; v[1] = (__bf16)T1; v[2] = (__bf16)T2; v[3] = (__bf16)T3;
    v[4] = (__bf16)T4; v[5] = (__bf16)T5; v[6] = (__bf16)T6; v[7] = (__bf16)T7;
    *(bf16x8*)(A + (size_t)i * 8) = v;
  } else if (i < N_BASIS + N_CONV) {
    int j = i - N_BASIS;
    const float4* p = (const float4*)(w + (size_t)j * 8);
    float4 a = p[0], b = p[1];
    bf16x8 v;
    v[0] = (__bf16)a.x; v[1] = (__bf16)a.y; v[2] = (__bf16)a.z; v[3] = (__bf16)a.w;
    v[4] = (__bf16)b.x; v[5] = (__bf16)b.y; v[6] = (__bf16)b.z; v[7] = (__bf16)b.w;
    *(bf16x8*)(B + (size_t)j * 8) = v;
  }
}

// ---------------- Pass 2: GEMM_BT + bias ----------------
#define BM 128
#define BN 128
#define BK 64
#define NT (KD / BK)       // 128 K-steps
#define TSZ (BN * BK)      // 8192 bf16 = 16 KB per B buffer

__global__ __launch_bounds__(256, 1) void gemm_bias(
    const __bf16* __restrict__ A, const __bf16* __restrict__ B,
    const float* __restrict__ bias, float* __restrict__ C) {
  __shared__ __align__(16) __bf16 Bs[3][TSZ];  // 48 KB (B only)

  const int tid = threadIdx.x;
  const int wave = tid >> 6;   // 0..3
  const int lane = tid & 63;

  // A-resident XCD swizzle (validated R10): b = xcd + 8*(nt + 8*mloc);
  // XCD k owns m-tiles {4k..4k+3}, n fastest -> A-tile L2/L3-served.
  const int b = blockIdx.x;
  const int xcd = b & 7;
  const int j = b >> 3;        // 0..31
  const int nt = j & 7;        // 0..7
  const int mloc = j >> 3;     // 0..3
  const int n0 = nt * BN;
  const int m0 = (xcd * 4 + mloc) * BM;

  const int wm = wave >> 1;    // 0..1
  const int wn = wave & 1;     // 0..1

  // ---- B staging (same as v9): one glds (16B/lane) covers 8 rows of 128B.
  // XOR swizzle on the GLOBAL side: slot (r,pg) holds logical group pg^ar.
  const int ar = lane >> 3;
  const int swz_col = ((lane & 7) ^ ar) * 8;
  const __bf16* gB = B + (size_t)(n0 + wave * 32 + ar) * KD + swz_col;
  const int loff = wave * 32 * BK;

  // ---- fragment coords (16x16x32: row=lane&15, k=(lane>>4)*8+jj)
  const int fr = lane & 15;
  const int fr7 = fr & 7;
  const int qk = lane >> 4;   // 0..3

  // ---- A direct-load pointers: lane's A-frag for (mi,s) is the 16B at
  // A[m0+wm*64+mi*16+fr][T*64 + s*32 + qk*8] — 64B-aligned segments.
  const __bf16* ap[4];
#pragma unroll
  for (int mi = 0; mi < 4; mi++)
    ap[mi] = A + (size_t)(m0 + wm * 64 + mi * 16 + fr) * KD + qk * 8;

  f32x4 acc[4][4];
#pragma unroll
  for (int i = 0; i < 4; i++)
#pragma unroll
    for (int jj = 0; jj < 4; jj++) acc[i][jj] = (f32x4){0.f, 0.f, 0.f, 0.f};

  // ---- prologue: stage(0) -> Bs[0] (4 ops); A(0) -> a_cur (8 ops)
#pragma unroll
  for (int jj = 0; jj < 4; jj++)
    __builtin_amdgcn_global_load_lds(
        (const __attribute__((address_space(1))) void*)(gB + (size_t)jj * 8 * KD),
        (__attribute__((address_space(3))) void*)(&Bs[0][loff + jj * 8 * BK]), 16, 0, 0);
  bf16x8 a_cur[4][2];
#pragma unroll
  for (int mi = 0; mi < 4; mi++)
#pragma unroll
    for (int s = 0; s < 2; s++)
      a_cur[mi][s] = *(const bf16x8*)(ap[mi] + s * 32);

  // Per iter T: pre-barrier {stage(T+1) -> Bs[NXT] (4), A(T+1) -> a_nxt (8)};
  // WAIT; s_barrier; post-barrier ds_read Bs[CUR] + 32 MFMA on a_cur; rotate.
  // vmcnt(12): the 12 newest = exactly this region's ops (bounded by the asm
  // memory clobbers), so stage(T) and A(T) are always complete. ITER(0) uses
  // vmcnt(0) (prologue region holds 12 ops too — belt-and-braces drain once).
  // Skew safety (1 barrier, 3 B-buffers): reads hit Bs[T%3]; in-flight DMA
  // targets Bs[(T+1)%3] / Bs[(T+2)%3] — disjoint.
#define ITER(T, CUR, NXT, WAIT)                                                \
  do {                                                                         \
    const int tn = ((T) + 1 < NT) ? (T) + 1 : 0;                               \
    _Pragma("unroll") for (int jj = 0; jj < 4; jj++)                           \
        __builtin_amdgcn_global_load_lds(                                      \
            (const __attribute__((address_space(1))) void*)(                   \
                gB + (size_t)tn * BK + (size_t)jj * 8 * KD),                   \
            (__attribute__((address_space(3))) void*)(                         \
                &Bs[NXT][loff + jj * 8 * BK]), 16, 0, 0);                      \
    bf16x8 a_nxt[4][2];                                                        \
    _Pragma("unroll") for (int mi = 0; mi < 4; mi++)                           \
        _Pragma("unroll") for (int s = 0; s < 2; s++)                          \
            a_nxt[mi][s] = *(const bf16x8*)(ap[mi] + tn * 64 + s * 32);        \
    asm volatile(WAIT ::: "memory");                                           \
    __builtin_amdgcn_s_barrier();                                              \
    asm volatile("" ::: "memory");                                             \
    _Pragma("unroll") for (int s = 0; s < 2; s++) {                            \
      const int pa = ((s * 4 + qk) ^ fr7) * 8;                                 \
      bf16x8 bfr[4];                                                           \
      _Pragma("unroll") for (int ni = 0; ni < 4; ni++)                         \
          bfr[ni] = *(const bf16x8*)&Bs[CUR][(wn * 64 + ni * 16 + fr) * BK + pa]; \
      _Pragma("unroll") for (int mi = 0; mi < 4; mi++)                         \
          _Pragma("unroll") for (int ni = 0; ni < 4; ni++)                     \
              acc[mi][ni] = __builtin_amdgcn_mfma_f32_16x16x32_bf16(           \
                  a_cur[mi][s], bfr[ni], acc[mi][ni], 0, 0, 0);                \
    }                                                                          \
    _Pragma("unroll") for (int mi = 0; mi < 4; mi++)                           \
        _Pragma("unroll") for (int s = 0; s < 2; s++)                          \
            a_cur[mi][s] = a_nxt[mi][s];                                       \
  } while (0)

  ITER(0, 0, 1, "s_waitcnt vmcnt(0)");   // full drain once
  ITER(1, 1, 2, "s_waitcnt vmcnt(12)");
  ITER(2, 2, 0, "s_waitcnt vmcnt(12)");
#pragma unroll 1
  for (int t0 = 3; t0 < 126; t0 += 3) {  // iters 3..125, buffer phase static
    ITER(t0, 0, 1, "s_waitcnt vmcnt(12)");
    ITER(t0 + 1, 1, 2, "s_waitcnt vmcnt(12)");
    ITER(t0 + 2, 2, 0, "s_waitcnt vmcnt(12)");
  }
  ITER(126, 0, 1, "s_waitcnt vmcnt(12)");
  ITER(127, 1, 2, "s_waitcnt vmcnt(12)");
#undef ITER

  // ---- epilogue (v9-proven): C/D col=lane&15, row=(lane>>4)*4+r ; add bias
  const int col0 = n0 + wn * 64;
  const int row0 = m0 + wm * 64 + qk * 4;
#pragma unroll
  for (int ni = 0; ni < 4; ni++) {
    int col = col0 + ni * 16 + fr;
    float bv = bias[col];
#pragma unroll
    for (int mi = 0; mi < 4; mi++) {
      int row = row0 + mi * 16;
#pragma unroll
      for (int r = 0; r < 4; r++)
        C[(size_t)(row + r) * ND + col] = acc[mi][ni][r] + bv;
    }
  }
}

extern "C" void kernel_launch(void* const* d_in, const int* in_sizes, int n_in,
                              void* d_out, int out_size, void* d_ws, size_t ws_size,
                              hipStream_t stream) {
  const float* x = (const float*)d_in[0];     // [4096,1024]
  const float* w = (const float*)d_in[1];     // [1024,1024,8]
  const float* bias = (const float*)d_in[2];  // [1024]
  float* out = (float*)d_out;                 // [4096,1024]

  __bf16* Abf = (__bf16*)d_ws;  // 4096*8192 bf16 = 64 MB
  __bf16* Bbf = (__bf16*)((char*)d_ws + (size_t)MD * KD * 2);  // 16 MB

  {  // merged basis + convert
    int n = N_BASIS + N_CONV;
    prep_kernel<<<(n + 255) / 256, 256, 0, stream>>>(x, w, Abf, Bbf);
  }
  {  // GEMM + bias: 256 blocks (128x128 tiles), 1 block/CU
    gemm_bias<<<256, 256, 0, stream>>>(Abf, Bbf, bias, out);
  }
}

// Round 14
// 179.013 us; speedup vs baseline: 1.4192x; 1.4192x over previous
//
#include <hip/hip_runtime.h>
#include <hip/hip_bf16.h>

// KAN layer = GEMM: out[b,o] = sum_{i,k} T_k(tanh(x[b,i])) * W[o,i,k] + bias[o]
// v11 = split-K: v9's 128x128 tile economy (512B ds_read/MFMA, the best
// possible at this size with a 2x2 wave grid) AND v8's 2-blocks/CU TLP
// (which ran the LDS unit at 95% of its throughput; v9's 1 block/CU got 58%).
//   512 blocks: (kh=0|1) x 32 m-tiles x 8 n-tiles; block does 128x128 x 4096.
//   LDS = 32KB single buffer -> 2 blocks/CU. Sync = v8's PROVEN plain
//   2-__syncthreads() loop (no counted vmcnt: drain hidden by the co-resident
//   block). Staging swizzle / fragment reads / epilogue = v9's proven code.
//   kh=0 writes C + bias; kh=1 writes fp32 partial P1 (ws); reduce adds them.
#define MD 4096
#define ND 1024
#define KD 8192
#define IN_F 1024

typedef __bf16 bf16x8 __attribute__((ext_vector_type(8)));
typedef float f32x4 __attribute__((ext_vector_type(4)));

// ---------------- Pass 1 (merged): basis + W convert ----------------
#define N_BASIS (MD * IN_F)
#define N_CONV ((ND * KD) / 8)

__global__ __launch_bounds__(256) void prep_kernel(
    const float* __restrict__ x, const float* __restrict__ w,
    __bf16* __restrict__ A, __bf16* __restrict__ B) {
  int i = blockIdx.x * blockDim.x + threadIdx.x;
  if (i < N_BASIS) {
    float t = tanhf(x[i]);
    float two_t = 2.0f * t;
    float T0 = 1.0f;
    float T1 = t;
    float T2 = two_t * T1 - T0;
    float T3 = two_t * T2 - T1;
    float T4 = two_t * T3 - T2;
    float T5 = two_t * T4 - T3;
    float T6 = two_t * T5 - T4;
    float T7 = two_t * T6 - T5;
    bf16x8 v;
    v[0] = (__bf16)T0; v[1] = (__bf16)T1; v[2] = (__bf16)T2; v[3] = (__bf16)T3;
    v[4] = (__bf16)T4; v[5] = (__bf16)T5; v[6] = (__bf16)T6; v[7] = (__bf16)T7;
    *(bf16x8*)(A + (size_t)i * 8) = v;
  } else if (i < N_BASIS + N_CONV) {
    int j = i - N_BASIS;
    const float4* p = (const float4*)(w + (size_t)j * 8);
    float4 a = p[0], b = p[1];
    bf16x8 v;
    v[0] = (__bf16)a.x; v[1] = (__bf16)a.y; v[2] = (__bf16)a.z; v[3] = (__bf16)a.w;
    v[4] = (__bf16)b.x; v[5] = (__bf16)b.y; v[6] = (__bf16)b.z; v[7] = (__bf16)b.w;
    *(bf16x8*)(B + (size_t)j * 8) = v;
  }
}

// ---------------- Pass 2: split-K GEMM_BT ----------------
#define BM 128
#define BN 128
#define BK 64
#define KHALF 4096
#define NTH (KHALF / BK)   // 64 K-steps per block
#define TSZ (BM * BK)      // 8192 bf16 = 16 KB per tile

__global__ __launch_bounds__(256) void gemm_bias(
    const __bf16* __restrict__ A, const __bf16* __restrict__ B,
    const float* __restrict__ bias, float* __restrict__ C,
    float* __restrict__ P1) {
  __shared__ __align__(16) __bf16 As[TSZ];  // 16 KB
  __shared__ __align__(16) __bf16 Bs[TSZ];  // 16 KB  -> 32 KB, 2 blocks/CU

  const int tid = threadIdx.x;
  const int wave = tid >> 6;   // 0..3
  const int lane = tid & 63;

  // A-resident XCD swizzle (R10-validated mechanism). 512 blocks:
  // b = xcd + 8*(nt + 8*(kh + 2*mloc)); XCD k owns m-tiles {4k..4k+3}.
  const int b = blockIdx.x;
  const int xcd = b & 7;
  const int j = b >> 3;        // 0..63
  const int nt = j & 7;        // 0..7
  const int kh = (j >> 3) & 1; // 0..1
  const int mloc = j >> 4;     // 0..3
  const int n0 = nt * BN;
  const int m0 = (xcd * 4 + mloc) * BM;
  const size_t k0 = (size_t)kh * KHALF;

  const int wm = wave >> 1;    // 0..1
  const int wn = wave & 1;     // 0..1

  // ---- staging (v9-proven): one glds (16B/lane) covers 8 rows of 128B.
  // XOR swizzle on the GLOBAL side: slot (r,pg) holds logical group pg^ar.
  const int ar = lane >> 3;
  const int swz_col = ((lane & 7) ^ ar) * 8;
  const __bf16* gA = A + (size_t)(m0 + wave * 32 + ar) * KD + k0 + swz_col;
  const __bf16* gB = B + (size_t)(n0 + wave * 32 + ar) * KD + k0 + swz_col;
  const int loff = wave * 32 * BK;

  f32x4 acc[4][4];
#pragma unroll
  for (int i = 0; i < 4; i++)
#pragma unroll
    for (int jj = 0; jj < 4; jj++) acc[i][jj] = (f32x4){0.f, 0.f, 0.f, 0.f};

  // ---- fragment coords (16x16x32: row=lane&15, k=(lane>>4)*8+jj)
  const int fr = lane & 15;
  const int fr7 = fr & 7;
  const int qk = lane >> 4;   // 0..3

  // ---- main loop: v8's PROVEN single-buffer 2-barrier pattern.
  for (int kt = 0; kt < KHALF; kt += BK) {
#pragma unroll
    for (int jj = 0; jj < 4; jj++) {
      __builtin_amdgcn_global_load_lds(
          (const __attribute__((address_space(1))) void*)(gA + kt + (size_t)jj * 8 * KD),
          (__attribute__((address_space(3))) void*)(&As[loff + jj * 8 * BK]), 16, 0, 0);
      __builtin_amdgcn_global_load_lds(
          (const __attribute__((address_space(1))) void*)(gB + kt + (size_t)jj * 8 * KD),
          (__attribute__((address_space(3))) void*)(&Bs[loff + jj * 8 * BK]), 16, 0, 0);
    }
    __syncthreads();

#pragma unroll
    for (int s = 0; s < 2; s++) {
      const int pa = ((s * 4 + qk) ^ fr7) * 8;
      bf16x8 af[4], bfr[4];
#pragma unroll
      for (int mi = 0; mi < 4; mi++)
        af[mi] = *(const bf16x8*)&As[(wm * 64 + mi * 16 + fr) * BK + pa];
#pragma unroll
      for (int ni = 0; ni < 4; ni++)
        bfr[ni] = *(const bf16x8*)&Bs[(wn * 64 + ni * 16 + fr) * BK + pa];
#pragma unroll
      for (int mi = 0; mi < 4; mi++)
#pragma unroll
        for (int ni = 0; ni < 4; ni++)
          acc[mi][ni] = __builtin_amdgcn_mfma_f32_16x16x32_bf16(
              af[mi], bfr[ni], acc[mi][ni], 0, 0, 0);
    }
    __syncthreads();
  }

  // ---- epilogue (v9-proven indexing): kh=0 -> C (+bias); kh=1 -> P1.
  float* dst = kh ? P1 : C;
  const int col0 = n0 + wn * 64;
  const int row0 = m0 + wm * 64 + qk * 4;
#pragma unroll
  for (int ni = 0; ni < 4; ni++) {
    int col = col0 + ni * 16 + fr;
    float bv = kh ? 0.0f : bias[col];
#pragma unroll
    for (int mi = 0; mi < 4; mi++) {
      int row = row0 + mi * 16;
#pragma unroll
      for (int r = 0; r < 4; r++)
        dst[(size_t)(row + r) * ND + col] = acc[mi][ni][r] + bv;
    }
  }
}

// ---------------- Pass 3: C += P1 (48 MB traffic, ~8 us) ----------------
__global__ __launch_bounds__(256) void reduce_kernel(
    float* __restrict__ C, const float* __restrict__ P1) {
  size_t i = (size_t)blockIdx.x * blockDim.x + threadIdx.x;  // f32x4 index
  f32x4 c = ((const f32x4*)C)[i];
  f32x4 p = ((const f32x4*)P1)[i];
#pragma unroll
  for (int r = 0; r < 4; r++) c[r] += p[r];
  ((f32x4*)C)[i] = c;
}

extern "C" void kernel_launch(void* const* d_in, const int* in_sizes, int n_in,
                              void* d_out, int out_size, void* d_ws, size_t ws_size,
                              hipStream_t stream) {
  const float* x = (const float*)d_in[0];     // [4096,1024]
  const float* w = (const float*)d_in[1];     // [1024,1024,8]
  const float* bias = (const float*)d_in[2];  // [1024]
  float* out = (float*)d_out;                 // [4096,1024]

  __bf16* Abf = (__bf16*)d_ws;                                   // 64 MB
  __bf16* Bbf = (__bf16*)((char*)d_ws + (size_t)MD * KD * 2);    // 16 MB
  float* P1 = (float*)((char*)d_ws + (size_t)MD * KD * 2 + (size_t)ND * KD * 2);  // 16 MB

  {  // merged basis + convert
    int n = N_BASIS + N_CONV;
    prep_kernel<<<(n + 255) / 256, 256, 0, stream>>>(x, w, Abf, Bbf);
  }
  {  // split-K GEMM: 512 blocks (2 per output tile), 2 blocks/CU
    gemm_bias<<<512, 256, 0, stream>>>(Abf, Bbf, bias, out, P1);
  }
  {  // merge the two K-halves: 4M floats / 4 per thread / 256 per block
    reduce_kernel<<<(MD * ND) / 4 / 256, 256, 0, stream>>>(out, P1);
  }
}